// Round 1
// baseline (2304.003 us; speedup 1.0000x reference)
//
#include <hip/hip_runtime.h>

#define IN_DIM 512
#define OUT_DIM 32
#define KSTEPS 10
#define ALPHA 0.1f

// ---------------- degree / norm kernels ----------------

__global__ void k_init_deg(float* __restrict__ deg, int N) {
    int i = blockIdx.x * blockDim.x + threadIdx.x;
    if (i < N) deg[i] = 1.0f;  // self-loop contributes 1
}

__global__ void k_count(const int* __restrict__ dst, float* __restrict__ deg, int E) {
    int e = blockIdx.x * blockDim.x + threadIdx.x;
    if (e < E) atomicAdd(&deg[dst[e]], 1.0f);
}

__global__ void k_rsqrt(float* __restrict__ deg, int N) {
    int i = blockIdx.x * blockDim.x + threadIdx.x;
    if (i < N) deg[i] = rsqrtf(deg[i]);  // deg >= 1 always (self-loops)
}

__global__ void k_edgew(const int* __restrict__ src, const int* __restrict__ dst,
                        const float* __restrict__ dinv, float* __restrict__ w, int E) {
    int e = blockIdx.x * blockDim.x + threadIdx.x;
    if (e < E) w[e] = dinv[src[e]] * dinv[dst[e]];
}

// ---------------- dense projection h = x @ W^T + b ----------------
// One thread per node. W/bias addresses are wave-uniform -> scalar loads.

__global__ __launch_bounds__(256) void k_gemm(const float* __restrict__ x,
                                              const float* __restrict__ W,
                                              const float* __restrict__ bias,
                                              float* __restrict__ h, int N) {
    int node = blockIdx.x * 256 + threadIdx.x;
    if (node >= N) return;
    const float4* xr = (const float4*)(x + (size_t)node * IN_DIM);
    float acc[OUT_DIM];
#pragma unroll
    for (int o = 0; o < OUT_DIM; o++) acc[o] = 0.0f;
    for (int k4 = 0; k4 < IN_DIM / 4; k4++) {
        float4 xv = xr[k4];
#pragma unroll
        for (int o = 0; o < OUT_DIM; o++) {
            float4 wv = *(const float4*)(W + o * IN_DIM + k4 * 4);
            acc[o] = fmaf(xv.x, wv.x, acc[o]);
            acc[o] = fmaf(xv.y, wv.y, acc[o]);
            acc[o] = fmaf(xv.z, wv.z, acc[o]);
            acc[o] = fmaf(xv.w, wv.w, acc[o]);
        }
    }
    float4* out = (float4*)(h + (size_t)node * OUT_DIM);
#pragma unroll
    for (int o4 = 0; o4 < OUT_DIM / 4; o4++) {
        out[o4] = make_float4(acc[4 * o4 + 0] + bias[4 * o4 + 0],
                              acc[4 * o4 + 1] + bias[4 * o4 + 1],
                              acc[4 * o4 + 2] + bias[4 * o4 + 2],
                              acc[4 * o4 + 3] + bias[4 * o4 + 3]);
    }
}

// ---------------- propagation kernels ----------------
// z_next initialized with the self-loop term dinv[i]^2 * z_prev[i]
// (also serves as the zero-init for the scatter).
__global__ void k_pre(const float4* __restrict__ zprev, const float* __restrict__ dinv,
                      float4* __restrict__ znext, int N8) {
    int t = blockIdx.x * blockDim.x + threadIdx.x;
    if (t < N8) {
        float d = dinv[t >> 3];
        d = d * d;
        float4 v = zprev[t];
        znext[t] = make_float4(v.x * d, v.y * d, v.z * d, v.w * d);
    }
}

// 32 threads per edge: coalesced 128B gather + 32 atomics to consecutive addrs.
__global__ void k_scatter(const int* __restrict__ src, const int* __restrict__ dst,
                          const float* __restrict__ w,
                          const float* __restrict__ zprev, float* __restrict__ znext,
                          int E) {
    int t = blockIdx.x * blockDim.x + threadIdx.x;
    int e = t >> 5;
    int c = t & 31;
    if (e < E) {
        float val = zprev[src[e] * OUT_DIM + c] * w[e];
        atomicAdd(&znext[dst[e] * OUT_DIM + c], val);
    }
}

// z_next = (1-alpha) * agg + alpha * h
__global__ void k_combine(float4* __restrict__ znext, const float4* __restrict__ h, int N8) {
    int t = blockIdx.x * blockDim.x + threadIdx.x;
    if (t < N8) {
        float4 a = znext[t];
        float4 hh = h[t];
        znext[t] = make_float4((1.0f - ALPHA) * a.x + ALPHA * hh.x,
                               (1.0f - ALPHA) * a.y + ALPHA * hh.y,
                               (1.0f - ALPHA) * a.z + ALPHA * hh.z,
                               (1.0f - ALPHA) * a.w + ALPHA * hh.w);
    }
}

extern "C" void kernel_launch(void* const* d_in, const int* in_sizes, int n_in,
                              void* d_out, int out_size, void* d_ws, size_t ws_size,
                              hipStream_t stream) {
    const float* x    = (const float*)d_in[0];
    const float* W    = (const float*)d_in[1];
    const float* bias = (const float*)d_in[2];
    const int*   ei   = (const int*)d_in[3];

    const int N = in_sizes[0] / IN_DIM;   // 100000
    const int E = in_sizes[3] / 2;        // 1600000
    const int* src = ei;
    const int* dst = ei + E;

    // workspace layout
    char* ws = (char*)d_ws;
    float* h    = (float*)ws;                                   // N*32 floats
    float* A    = (float*)(ws + (size_t)N * OUT_DIM * 4);       // N*32 floats
    float* dinv = (float*)(ws + (size_t)N * OUT_DIM * 8);       // N floats (deg in-place)
    float* w    = (float*)(ws + (size_t)N * OUT_DIM * 8 + (size_t)N * 4);  // E floats

    const int B = 256;
    int gN   = (N + B - 1) / B;
    int gE   = (E + B - 1) / B;
    int N8   = N * (OUT_DIM / 4);
    int gN8  = (N8 + B - 1) / B;
    long long ec = (long long)E * OUT_DIM;
    int gEC  = (int)((ec + B - 1) / B);

    // degree + normalization weights
    k_init_deg<<<gN, B, 0, stream>>>(dinv, N);
    k_count<<<gE, B, 0, stream>>>(dst, dinv, E);
    k_rsqrt<<<gN, B, 0, stream>>>(dinv, N);
    k_edgew<<<gE, B, 0, stream>>>(src, dst, dinv, w, E);

    // dense projection
    k_gemm<<<gN, B, 0, stream>>>(x, W, bias, h, N);

    // K propagation steps; ping-pong A <-> d_out so step 10 lands in d_out
    float* zprev = h;
    for (int s = 0; s < KSTEPS; s++) {
        float* znext = (s % 2 == 0) ? A : (float*)d_out;
        k_pre<<<gN8, B, 0, stream>>>((const float4*)zprev, dinv, (float4*)znext, N8);
        k_scatter<<<gEC, B, 0, stream>>>(src, dst, w, zprev, znext, E);
        k_combine<<<gN8, B, 0, stream>>>((float4*)znext, (const float4*)h, N8);
        zprev = znext;
    }
}

// Round 2
// 2190.118 us; speedup vs baseline: 1.0520x; 1.0520x over previous
//
#include <hip/hip_runtime.h>

#define IN_DIM 512
#define OUT_DIM 32
#define KSTEPS 10
#define ALPHA 0.1f

// ---------------- degree / norm ----------------

__global__ void k_count(const int* __restrict__ dst, int* __restrict__ cnt, int E) {
    int e = blockIdx.x * blockDim.x + threadIdx.x;
    if (e < E) atomicAdd(&cnt[dst[e]], 1);
}

__global__ void k_rsqrt(const int* __restrict__ cnt, float* __restrict__ dinv, int N) {
    int i = blockIdx.x * blockDim.x + threadIdx.x;
    if (i < N) dinv[i] = rsqrtf((float)cnt[i] + 1.0f);  // +1 self-loop
}

// Exclusive prefix sum over N counts, single workgroup of 1024 threads.
__global__ __launch_bounds__(1024) void k_scan(const int* __restrict__ cnt,
                                               int* __restrict__ off, int N) {
    __shared__ int partials[1024];
    int t = threadIdx.x;
    int chunk = (N + 1023) / 1024;
    int lo = t * chunk;
    int hi = lo + chunk; if (hi > N) hi = N; if (lo > N) lo = N;
    int s = 0;
    for (int i = lo; i < hi; i++) s += cnt[i];
    partials[t] = s;
    __syncthreads();
    // Hillis-Steele inclusive scan
    for (int d = 1; d < 1024; d <<= 1) {
        int v = (t >= d) ? partials[t - d] : 0;
        __syncthreads();
        partials[t] += v;
        __syncthreads();
    }
    int base = (t == 0) ? 0 : partials[t - 1];
    for (int i = lo; i < hi; i++) { off[i] = base; base += cnt[i]; }
    if (t == 0) off[N] = partials[1023];
}

// Fill CSR records (w, src) bucketed by dst. Order within a bucket is irrelevant.
__global__ void k_fill(const int* __restrict__ src, const int* __restrict__ dst,
                       const float* __restrict__ dinv, const int* __restrict__ off,
                       int* __restrict__ cur, float2* __restrict__ csr, int E) {
    int e = blockIdx.x * blockDim.x + threadIdx.x;
    if (e < E) {
        int d = dst[e], s = src[e];
        int pos = off[d] + atomicAdd(&cur[d], 1);
        csr[pos] = make_float2(dinv[s] * dinv[d], __int_as_float(s));
    }
}

// ---------------- dense projection h = x @ W^T + b ----------------
// 4 threads per node, 8 outputs each: 1563 blocks -> good occupancy.
// The node's 4 lanes read the same x chunk (HW broadcast) -> x fetched once.

__global__ __launch_bounds__(256) void k_gemm(const float* __restrict__ x,
                                              const float* __restrict__ W,
                                              const float* __restrict__ bias,
                                              float* __restrict__ h, int N) {
    int t = blockIdx.x * 256 + threadIdx.x;
    int node = t >> 2;
    int og = (t & 3) * 8;  // first of this thread's 8 output channels
    if (node >= N) return;
    const float4* xr = (const float4*)(x + (size_t)node * IN_DIM);
    float acc[8];
#pragma unroll
    for (int o = 0; o < 8; o++) acc[o] = 0.0f;
    for (int k4 = 0; k4 < IN_DIM / 4; k4++) {
        float4 xv = xr[k4];
#pragma unroll
        for (int o = 0; o < 8; o++) {
            float4 wv = *(const float4*)(W + (size_t)(og + o) * IN_DIM + k4 * 4);
            acc[o] = fmaf(xv.x, wv.x, acc[o]);
            acc[o] = fmaf(xv.y, wv.y, acc[o]);
            acc[o] = fmaf(xv.z, wv.z, acc[o]);
            acc[o] = fmaf(xv.w, wv.w, acc[o]);
        }
    }
    float4* out = (float4*)(h + (size_t)node * OUT_DIM + og);
#pragma unroll
    for (int o4 = 0; o4 < 2; o4++) {
        out[o4] = make_float4(acc[4 * o4 + 0] + bias[og + 4 * o4 + 0],
                              acc[4 * o4 + 1] + bias[og + 4 * o4 + 1],
                              acc[4 * o4 + 2] + bias[og + 4 * o4 + 2],
                              acc[4 * o4 + 3] + bias[og + 4 * o4 + 3]);
    }
}

// ---------------- propagation: pull-based, atomic-free, fully fused ----------
// 32 lanes per dst node (lane = channel). Edge record: 8B broadcast load.
// z gather: 32 consecutive floats = coalesced 128B line (z is L2/L3 resident).
// z_next = (1-a) * (sum_{e in N(i)} w_e * z[src_e] + dinv_i^2 * z_i) + a * h_i

__global__ __launch_bounds__(256) void k_pull(const int* __restrict__ off,
                                              const float2* __restrict__ csr,
                                              const float* __restrict__ zprev,
                                              const float* __restrict__ h,
                                              const float* __restrict__ dinv,
                                              float* __restrict__ znext, int N) {
    int t = blockIdx.x * 256 + threadIdx.x;
    int node = t >> 5;
    int c = t & 31;
    if (node >= N) return;
    int beg = off[node], end = off[node + 1];
    float acc = 0.0f;
    for (int j = beg; j < end; j++) {
        float2 rec = csr[j];
        int s = __float_as_int(rec.y);
        acc = fmaf(rec.x, zprev[(size_t)s * OUT_DIM + c], acc);
    }
    float d = dinv[node];
    acc = fmaf(d * d, zprev[(size_t)node * OUT_DIM + c], acc);
    znext[t] = fmaf(1.0f - ALPHA, acc, ALPHA * h[t]);
}

extern "C" void kernel_launch(void* const* d_in, const int* in_sizes, int n_in,
                              void* d_out, int out_size, void* d_ws, size_t ws_size,
                              hipStream_t stream) {
    const float* x    = (const float*)d_in[0];
    const float* W    = (const float*)d_in[1];
    const float* bias = (const float*)d_in[2];
    const int*   ei   = (const int*)d_in[3];

    const int N = in_sizes[0] / IN_DIM;   // 100000
    const int E = in_sizes[3] / 2;        // 1600000
    const int* src = ei;
    const int* dst = ei + E;

    // workspace layout (all 16B-aligned)
    char* ws = (char*)d_ws;
    size_t o = 0;
    float*  h    = (float*)(ws + o);  o += (size_t)N * OUT_DIM * 4;   // 12.8 MB
    float*  A    = (float*)(ws + o);  o += (size_t)N * OUT_DIM * 4;   // 12.8 MB
    float2* csr  = (float2*)(ws + o); o += (size_t)E * 8;             // 12.8 MB
    float*  dinv = (float*)(ws + o);  o += (size_t)N * 4;
    int*    off  = (int*)(ws + o);    o += (size_t)(N + 1) * 4;
    int*    cnt  = (int*)(ws + o);    o += (size_t)N * 4;
    int*    cur  = (int*)(ws + o);    o += (size_t)N * 4;

    const int B = 256;
    int gN  = (N + B - 1) / B;
    int gE  = (E + B - 1) / B;
    int gP  = ((size_t)N * OUT_DIM + B - 1) / B;
    int gG  = ((size_t)N * 4 + B - 1) / B;

    // cnt and cur are adjacent except off sits between... zero them separately
    hipMemsetAsync(cnt, 0, (size_t)N * 4 * 2 + 0, stream);  // zeros cnt AND cur (adjacent)

    // degree + norm + CSR
    k_count<<<gE, B, 0, stream>>>(dst, cnt, E);
    k_rsqrt<<<gN, B, 0, stream>>>(cnt, dinv, N);
    k_scan<<<1, 1024, 0, stream>>>(cnt, off, N);
    k_fill<<<gE, B, 0, stream>>>(src, dst, dinv, off, cur, csr, E);

    // dense projection
    k_gemm<<<gG, B, 0, stream>>>(x, W, bias, h, N);

    // K propagation steps; ping-pong A <-> d_out so step 10 lands in d_out
    const float* zprev = h;
    for (int s = 0; s < KSTEPS; s++) {
        float* znext = (s % 2 == 0) ? A : (float*)d_out;
        k_pull<<<gP, B, 0, stream>>>(off, csr, zprev, h, dinv, znext, N);
        zprev = znext;
    }
}

// Round 3
// 1179.315 us; speedup vs baseline: 1.9537x; 1.8571x over previous
//
#include <hip/hip_runtime.h>

#define IN_DIM 512
#define OUT_DIM 32
#define KSTEPS 10
#define ALPHA 0.1f
#define KSPLIT 4
#define KCHUNK (IN_DIM / KSPLIT)  // 128

// ---------------- degree / norm / CSR build ----------------

__global__ void k_count(const int* __restrict__ dst, int* __restrict__ cnt, int E) {
    int e = blockIdx.x * blockDim.x + threadIdx.x;
    if (e < E) atomicAdd(&cnt[dst[e]], 1);
}

__global__ void k_rsqrt(const int* __restrict__ cnt, float* __restrict__ dinv, int N) {
    int i = blockIdx.x * blockDim.x + threadIdx.x;
    if (i < N) dinv[i] = rsqrtf((float)cnt[i] + 1.0f);  // +1 self-loop
}

// Exclusive prefix sum over N counts, single workgroup of 1024 threads.
__global__ __launch_bounds__(1024) void k_scan(const int* __restrict__ cnt,
                                               int* __restrict__ off, int N) {
    __shared__ int partials[1024];
    int t = threadIdx.x;
    int chunk = (N + 1023) / 1024;
    int lo = t * chunk;
    int hi = lo + chunk; if (hi > N) hi = N; if (lo > N) lo = N;
    int s = 0;
    for (int i = lo; i < hi; i++) s += cnt[i];
    partials[t] = s;
    __syncthreads();
    for (int d = 1; d < 1024; d <<= 1) {
        int v = (t >= d) ? partials[t - d] : 0;
        __syncthreads();
        partials[t] += v;
        __syncthreads();
    }
    int base = (t == 0) ? 0 : partials[t - 1];
    for (int i = lo; i < hi; i++) { off[i] = base; base += cnt[i]; }
    if (t == 0) off[N] = partials[1023];
}

// Fill CSR records (w, src) bucketed by dst.
__global__ void k_fill(const int* __restrict__ src, const int* __restrict__ dst,
                       const float* __restrict__ dinv, const int* __restrict__ off,
                       int* __restrict__ cur, float2* __restrict__ csr, int E) {
    int e = blockIdx.x * blockDim.x + threadIdx.x;
    if (e < E) {
        int d = dst[e], s = src[e];
        int pos = off[d] + atomicAdd(&cur[d], 1);
        csr[pos] = make_float2(dinv[s] * dinv[d], __int_as_float(s));
    }
}

// ---------------- dense projection, K-split ----------------
// 1 thread per node per K-chunk: W addresses depend only on blockIdx ->
// wave-uniform -> scalar s_load path (R0's 112-SGPR structure), but 4x the
// blocks of R0 for occupancy. Partials combined afterwards.

__global__ __launch_bounds__(256) void k_gemm_part(const float* __restrict__ x,
                                                   const float* __restrict__ W,
                                                   float* __restrict__ p0,
                                                   float* __restrict__ p1,
                                                   float* __restrict__ p2,
                                                   float* __restrict__ p3, int N) {
    int nb = blockIdx.x >> 2;
    int ks = blockIdx.x & 3;
    int node = nb * 256 + threadIdx.x;
    if (node >= N) return;
    const float4* xr = (const float4*)(x + (size_t)node * IN_DIM + ks * KCHUNK);
    const float* Wk = W + ks * KCHUNK;
    float acc[OUT_DIM];
#pragma unroll
    for (int o = 0; o < OUT_DIM; o++) acc[o] = 0.0f;
    for (int k4 = 0; k4 < KCHUNK / 4; k4++) {
        float4 xv = xr[k4];
#pragma unroll
        for (int o = 0; o < OUT_DIM; o++) {
            float4 wv = *(const float4*)(Wk + (size_t)o * IN_DIM + k4 * 4);
            acc[o] = fmaf(xv.x, wv.x, acc[o]);
            acc[o] = fmaf(xv.y, wv.y, acc[o]);
            acc[o] = fmaf(xv.z, wv.z, acc[o]);
            acc[o] = fmaf(xv.w, wv.w, acc[o]);
        }
    }
    float* p = (ks == 0) ? p0 : (ks == 1) ? p1 : (ks == 2) ? p2 : p3;
    float4* out = (float4*)(p + (size_t)node * OUT_DIM);
#pragma unroll
    for (int o4 = 0; o4 < OUT_DIM / 4; o4++)
        out[o4] = make_float4(acc[4 * o4 + 0], acc[4 * o4 + 1],
                              acc[4 * o4 + 2], acc[4 * o4 + 3]);
}

__global__ void k_combine(const float4* __restrict__ p0, const float4* __restrict__ p1,
                          const float4* __restrict__ p2, const float4* __restrict__ p3,
                          const float* __restrict__ bias, float4* __restrict__ h, int n4) {
    int t = blockIdx.x * blockDim.x + threadIdx.x;
    if (t < n4) {
        float4 a = p0[t], b = p1[t], c = p2[t], d = p3[t];
        float4 bb = ((const float4*)bias)[t & 7];
        h[t] = make_float4(a.x + b.x + c.x + d.x + bb.x,
                           a.y + b.y + c.y + d.y + bb.y,
                           a.z + b.z + c.z + d.z + bb.z,
                           a.w + b.w + c.w + d.w + bb.w);
    }
}

// ---------------- propagation: pull-based, unroll-4 for MLP ----------------
// 32 lanes per dst node (lane = channel). 4 independent gather chains.

__global__ __launch_bounds__(256) void k_pull(const int* __restrict__ off,
                                              const float2* __restrict__ csr,
                                              const float* __restrict__ zprev,
                                              const float* __restrict__ h,
                                              const float* __restrict__ dinv,
                                              float* __restrict__ znext, int N) {
    int t = blockIdx.x * 256 + threadIdx.x;
    int node = t >> 5;
    int c = t & 31;
    if (node >= N) return;
    int beg = off[node], end = off[node + 1];
    float acc0 = 0.0f, acc1 = 0.0f, acc2 = 0.0f, acc3 = 0.0f;
    int j = beg;
    for (; j + 4 <= end; j += 4) {
        float2 r0 = csr[j + 0];
        float2 r1 = csr[j + 1];
        float2 r2 = csr[j + 2];
        float2 r3 = csr[j + 3];
        float z0 = zprev[(size_t)__float_as_int(r0.y) * OUT_DIM + c];
        float z1 = zprev[(size_t)__float_as_int(r1.y) * OUT_DIM + c];
        float z2 = zprev[(size_t)__float_as_int(r2.y) * OUT_DIM + c];
        float z3 = zprev[(size_t)__float_as_int(r3.y) * OUT_DIM + c];
        acc0 = fmaf(r0.x, z0, acc0);
        acc1 = fmaf(r1.x, z1, acc1);
        acc2 = fmaf(r2.x, z2, acc2);
        acc3 = fmaf(r3.x, z3, acc3);
    }
    for (; j < end; j++) {
        float2 r = csr[j];
        acc0 = fmaf(r.x, zprev[(size_t)__float_as_int(r.y) * OUT_DIM + c], acc0);
    }
    float acc = (acc0 + acc1) + (acc2 + acc3);
    float d = dinv[node];
    acc = fmaf(d * d, zprev[(size_t)node * OUT_DIM + c], acc);
    znext[t] = fmaf(1.0f - ALPHA, acc, ALPHA * h[t]);
}

extern "C" void kernel_launch(void* const* d_in, const int* in_sizes, int n_in,
                              void* d_out, int out_size, void* d_ws, size_t ws_size,
                              hipStream_t stream) {
    const float* x    = (const float*)d_in[0];
    const float* W    = (const float*)d_in[1];
    const float* bias = (const float*)d_in[2];
    const int*   ei   = (const int*)d_in[3];

    const int N = in_sizes[0] / IN_DIM;   // 100000
    const int E = in_sizes[3] / 2;        // 1600000
    const int* src = ei;
    const int* dst = ei + E;

    // workspace layout (16B-aligned pieces)
    char* ws = (char*)d_ws;
    size_t o = 0;
    float*  h    = (float*)(ws + o);  o += (size_t)N * OUT_DIM * 4;   // 12.8 MB
    float*  A    = (float*)(ws + o);  o += (size_t)N * OUT_DIM * 4;   // 12.8 MB
    float2* csr  = (float2*)(ws + o); o += (size_t)E * 8;             // 12.8 MB
    float*  P2   = (float*)(ws + o);  o += (size_t)N * OUT_DIM * 4;   // 12.8 MB
    float*  P3   = (float*)(ws + o);  o += (size_t)N * OUT_DIM * 4;   // 12.8 MB
    float*  dinv = (float*)(ws + o);  o += (size_t)N * 4;
    int*    off  = (int*)(ws + o);    o += (size_t)(N + 1) * 4;
    int*    cnt  = (int*)(ws + o);    o += (size_t)N * 4;
    int*    cur  = (int*)(ws + o);    o += (size_t)N * 4;

    const int B = 256;
    int gN = (N + B - 1) / B;
    int gE = (E + B - 1) / B;
    int gP = ((size_t)N * OUT_DIM + B - 1) / B;          // pull grid (12500)
    int gG = gN * KSPLIT;                                // gemm grid (1564)
    int n4 = N * OUT_DIM / 4;
    int gC = (n4 + B - 1) / B;

    hipMemsetAsync(cnt, 0, (size_t)N * 4 * 2, stream);   // zeros cnt AND cur (adjacent)

    // degree + norm + CSR
    k_count<<<gE, B, 0, stream>>>(dst, cnt, E);
    k_rsqrt<<<gN, B, 0, stream>>>(cnt, dinv, N);
    k_scan<<<1, 1024, 0, stream>>>(cnt, off, N);
    k_fill<<<gE, B, 0, stream>>>(src, dst, dinv, off, cur, csr, E);

    // dense projection: partials in A, d_out, P2, P3 (all free pre-propagation)
    float* p1 = (float*)d_out;
    k_gemm_part<<<gG, B, 0, stream>>>(x, W, A, p1, P2, P3, N);
    k_combine<<<gC, B, 0, stream>>>((const float4*)A, (const float4*)p1,
                                    (const float4*)P2, (const float4*)P3,
                                    bias, (float4*)h, n4);

    // K propagation steps; ping-pong A <-> d_out so step 10 lands in d_out
    const float* zprev = h;
    for (int s = 0; s < KSTEPS; s++) {
        float* znext = (s % 2 == 0) ? A : (float*)d_out;
        k_pull<<<gP, B, 0, stream>>>(off, csr, zprev, h, dinv, znext, N);
        zprev = znext;
    }
}